// Round 2
// baseline (210.685 us; speedup 1.0000x reference)
//
#include <hip/hip_runtime.h>

// Problem constants (from reference)
static constexpr int  B_  = 524288;
static constexpr int  K_  = 17;
static constexpr int  BK  = B_ * K_;            // 8912896 (b,k) pairs
static constexpr int  NTH = BK / 8;             // 1114112 threads, 8 pairs each
static constexpr long long OFF_Z   = (long long)BK * 2;  // floats (after gt_xy)
static constexpr long long OFF_IDX = OFF_Z + BK;         // floats (after gt_loc_z)

#define MAXXY 504.0f   // (64-1)*8.0
#define MAXZ  3.15f    // (64-1)*0.05

using v4f = __attribute__((ext_vector_type(4))) float;

__global__ __launch_bounds__(256)
void kp_gt_kernel(const v4f* __restrict__ in4, float* __restrict__ out) {
    int i = blockIdx.x * blockDim.x + threadIdx.x;
    if (i >= NTH) return;

    // 8 pairs = 24 consecutive input floats = 6 x 16B non-temporal loads
    v4f v[6];
#pragma unroll
    for (int q = 0; q < 6; ++q)
        v[q] = __builtin_nontemporal_load(&in4[6LL * i + q]);

    float f[24];
#pragma unroll
    for (int q = 0; q < 6; ++q) {
        f[4 * q + 0] = v[q].x; f[4 * q + 1] = v[q].y;
        f[4 * q + 2] = v[q].z; f[4 * q + 3] = v[q].w;
    }

    float cx[8], cy[8], cz[8], fx[8], fy[8];
#pragma unroll
    for (int j = 0; j < 8; ++j) {
        cx[j] = fminf(fmaxf(f[3 * j + 0], 0.0f), MAXXY);
        cy[j] = fminf(fmaxf(f[3 * j + 1], 0.0f), MAXXY);
        cz[j] = fminf(fmaxf(f[3 * j + 2], 0.0f), MAXZ);
        // *0.125f is bit-exact vs /8.0f; non-negative after clip so
        // (int) truncation == astype(int32)
        fx[j] = (float)(int)(cx[j] * 0.125f);
        fy[j] = (float)(int)(cy[j] * 0.125f);
    }

    // batch index b = pair/17 : one division + incremental carry across 8 pairs
    int p0 = 8 * i;
    int b0 = p0 / 17;
    int r  = p0 - b0 * 17;
    float fb[8];
#pragma unroll
    for (int j = 0; j < 8; ++j) {
        fb[j] = (float)b0;
        if (++r == 17) { r = 0; ++b0; }
    }

    // out[0 .. 2*BK)         : gt_xy [B,K,2] — 16 floats -> 4 nt stores
    v4f* oxy = (v4f*)out;
#pragma unroll
    for (int q = 0; q < 4; ++q) {
        v4f w = {cx[2 * q], cy[2 * q], cx[2 * q + 1], cy[2 * q + 1]};
        __builtin_nontemporal_store(w, &oxy[4LL * i + q]);
    }

    // out[OFF_Z .. OFF_Z+BK) : gt_loc_z [B*K] — 8 floats -> 2 nt stores
    v4f* oz = (v4f*)(out + OFF_Z);
    {
        v4f w0 = {cz[0], cz[1], cz[2], cz[3]};
        v4f w1 = {cz[4], cz[5], cz[6], cz[7]};
        __builtin_nontemporal_store(w0, &oz[2LL * i + 0]);
        __builtin_nontemporal_store(w1, &oz[2LL * i + 1]);
    }

    // out[OFF_IDX .. +3*BK)  : gt_index_z [B*K,3] — 24 floats -> 6 nt stores
    {
        float t[24];
#pragma unroll
        for (int j = 0; j < 8; ++j) {
            t[3 * j + 0] = fb[j];
            t[3 * j + 1] = fx[j];
            t[3 * j + 2] = fy[j];
        }
        v4f* oi = (v4f*)(out + OFF_IDX);
#pragma unroll
        for (int q = 0; q < 6; ++q) {
            v4f w = {t[4 * q], t[4 * q + 1], t[4 * q + 2], t[4 * q + 3]};
            __builtin_nontemporal_store(w, &oi[6LL * i + q]);
        }
    }
}

extern "C" void kernel_launch(void* const* d_in, const int* in_sizes, int n_in,
                              void* d_out, int out_size, void* d_ws, size_t ws_size,
                              hipStream_t stream) {
    const v4f* in4 = (const v4f*)d_in[0];
    float* out = (float*)d_out;
    const int block = 256;
    const int grid  = (NTH + block - 1) / block;  // 4352 blocks
    kp_gt_kernel<<<grid, block, 0, stream>>>(in4, out);
}

// Round 3
// 57.194 us; speedup vs baseline: 3.6837x; 3.6837x over previous
//
#include <hip/hip_runtime.h>

// Problem constants (from reference)
static constexpr int  B_  = 524288;
static constexpr int  K_  = 17;
static constexpr int  BK  = B_ * K_;            // 8912896 (b,k) pairs
static constexpr int  NTH = BK / 4;             // 2228224 threads, 4 pairs each
static constexpr long long OFF_Z   = (long long)BK * 2;  // floats (after gt_xy)
static constexpr long long OFF_IDX = OFF_Z + BK;         // floats (after gt_loc_z)

#define MAXXY 504.0f   // (64-1)*8.0
#define MAXZ  3.15f    // (64-1)*0.05

using v4f = __attribute__((ext_vector_type(4))) float;

// xorshift swizzle: bijective on [0,512); spreads write-entry stride-2 pattern
// across all 32 LDS banks while keeping dense reads conflict-free.
__device__ __forceinline__ int swz(int e) { return e ^ (e >> 3); }

__global__ __launch_bounds__(256)
void kp_gt_kernel(const v4f* __restrict__ in4, float* __restrict__ out) {
    // Block covers 1024 pairs. Outputs transposed via LDS so every global
    // store instruction is lane-dense (full 64B-line coverage).
    __shared__ v4f lds_xy[512];    // 8 KB: block's gt_xy  (1024 pairs * 2 floats)
    __shared__ v4f lds_idx[768];   // 12 KB: block's gt_index_z (1024 * 3 floats)

    const int t   = threadIdx.x;
    const int blk = blockIdx.x;
    const int u   = blk * 256 + t;          // global thread id; owns pairs 4u..4u+3

    // 4 pairs = 12 consecutive floats = 3 float4 loads
    const v4f v0 = in4[3LL * u + 0];
    const v4f v1 = in4[3LL * u + 1];
    const v4f v2 = in4[3LL * u + 2];

    const float px[4] = {v0.x, v0.w, v1.z, v2.y};
    const float py[4] = {v0.y, v1.x, v1.w, v2.z};
    const float pz[4] = {v0.z, v1.y, v2.x, v2.w};

    float cx[4], cy[4], cz[4], fx[4], fy[4];
#pragma unroll
    for (int j = 0; j < 4; ++j) {
        cx[j] = fminf(fmaxf(px[j], 0.0f), MAXXY);
        cy[j] = fminf(fmaxf(py[j], 0.0f), MAXXY);
        cz[j] = fminf(fmaxf(pz[j], 0.0f), MAXZ);
        // *0.125f bit-exact vs /8.0f; non-negative after clip so (int) == astype(int32)
        fx[j] = (float)(int)(cx[j] * 0.125f);
        fy[j] = (float)(int)(cy[j] * 0.125f);
    }

    // batch index b = pair/17
    int p0 = 4 * u;
    int b0 = p0 / 17;
    int r  = p0 - b0 * 17;
    float fb[4];
#pragma unroll
    for (int j = 0; j < 4; ++j) {
        fb[j] = (float)b0;
        if (++r == 17) { r = 0; ++b0; }
    }

    // ---- z stream: already per-thread dense (4 pairs == one float4) ----
    v4f* oz = (v4f*)(out + OFF_Z);
    oz[u] = (v4f){cz[0], cz[1], cz[2], cz[3]};

    // ---- xy -> LDS (swizzled) ----
    lds_xy[swz(2 * t + 0)] = (v4f){cx[0], cy[0], cx[1], cy[1]};
    lds_xy[swz(2 * t + 1)] = (v4f){cx[2], cy[2], cx[3], cy[3]};

    // ---- idx -> LDS (stride-3 writes already hit all banks; no swizzle) ----
    {
        float tt[12];
#pragma unroll
        for (int j = 0; j < 4; ++j) {
            tt[3 * j + 0] = fb[j];
            tt[3 * j + 1] = fx[j];
            tt[3 * j + 2] = fy[j];
        }
        lds_idx[3 * t + 0] = (v4f){tt[0], tt[1], tt[2],  tt[3]};
        lds_idx[3 * t + 1] = (v4f){tt[4], tt[5], tt[6],  tt[7]};
        lds_idx[3 * t + 2] = (v4f){tt[8], tt[9], tt[10], tt[11]};
    }

    __syncthreads();

    // ---- dense global stores: 64 lanes x 16B = contiguous 1KB per instruction ----
    v4f* oxy = (v4f*)out;
    oxy[(long long)blk * 512 + t      ] = lds_xy[swz(t)];
    oxy[(long long)blk * 512 + 256 + t] = lds_xy[swz(t + 256)];

    v4f* oi = (v4f*)(out + OFF_IDX);
    oi[(long long)blk * 768 + t      ] = lds_idx[t      ];
    oi[(long long)blk * 768 + 256 + t] = lds_idx[t + 256];
    oi[(long long)blk * 768 + 512 + t] = lds_idx[t + 512];
}

extern "C" void kernel_launch(void* const* d_in, const int* in_sizes, int n_in,
                              void* d_out, int out_size, void* d_ws, size_t ws_size,
                              hipStream_t stream) {
    const v4f* in4 = (const v4f*)d_in[0];
    float* out = (float*)d_out;
    const int block = 256;
    const int grid  = NTH / block;  // 8704 blocks, exact
    kp_gt_kernel<<<grid, block, 0, stream>>>(in4, out);
}

// Round 4
// 50.674 us; speedup vs baseline: 4.1576x; 1.1287x over previous
//
#include <hip/hip_runtime.h>

// Problem constants (from reference)
static constexpr int  B_  = 524288;
static constexpr int  K_  = 17;
static constexpr int  BK  = B_ * K_;            // 8912896 (b,k) pairs
static constexpr int  NTH = BK / 4;             // 2228224 threads, 4 pairs each
static constexpr long long OFF_Z   = (long long)BK * 2;  // floats (after gt_xy)
static constexpr long long OFF_IDX = OFF_Z + BK;         // floats (after gt_loc_z)

#define MAXXY 504.0f   // (64-1)*8.0
#define MAXZ  3.15f    // (64-1)*0.05

using v4f = __attribute__((ext_vector_type(4))) float;

// xorshift swizzle: bijective on [0,512); spreads write-entry stride-2 pattern
// across all 32 LDS banks while keeping dense reads conflict-free.
__device__ __forceinline__ int swz(int e) { return e ^ (e >> 3); }

__global__ __launch_bounds__(256)
void kp_gt_kernel(const v4f* __restrict__ in4, float* __restrict__ out) {
    // Block covers 1024 pairs. Outputs transposed via LDS so every global
    // store instruction is lane-dense (full 64B-line coverage) -> safe to
    // stream past L2/L3 with non-temporal stores (outputs have zero reuse).
    __shared__ v4f lds_xy[512];    // 8 KB: block's gt_xy  (1024 pairs * 2 floats)
    __shared__ v4f lds_idx[768];   // 12 KB: block's gt_index_z (1024 * 3 floats)

    const int t   = threadIdx.x;
    const int blk = blockIdx.x;
    const int u   = blk * 256 + t;          // global thread id; owns pairs 4u..4u+3

    // 4 pairs = 12 consecutive floats = 3 float4 loads (regular: reads want L3)
    const v4f v0 = in4[3LL * u + 0];
    const v4f v1 = in4[3LL * u + 1];
    const v4f v2 = in4[3LL * u + 2];

    const float px[4] = {v0.x, v0.w, v1.z, v2.y};
    const float py[4] = {v0.y, v1.x, v1.w, v2.z};
    const float pz[4] = {v0.z, v1.y, v2.x, v2.w};

    float cx[4], cy[4], cz[4], fx[4], fy[4];
#pragma unroll
    for (int j = 0; j < 4; ++j) {
        cx[j] = fminf(fmaxf(px[j], 0.0f), MAXXY);
        cy[j] = fminf(fmaxf(py[j], 0.0f), MAXXY);
        cz[j] = fminf(fmaxf(pz[j], 0.0f), MAXZ);
        // *0.125f bit-exact vs /8.0f; non-negative after clip so (int) == astype(int32)
        fx[j] = (float)(int)(cx[j] * 0.125f);
        fy[j] = (float)(int)(cy[j] * 0.125f);
    }

    // batch index b = pair/17
    int p0 = 4 * u;
    int b0 = p0 / 17;
    int r  = p0 - b0 * 17;
    float fb[4];
#pragma unroll
    for (int j = 0; j < 4; ++j) {
        fb[j] = (float)b0;
        if (++r == 17) { r = 0; ++b0; }
    }

    // ---- z stream: per-thread dense (4 pairs == one float4), nt store ----
    v4f* oz = (v4f*)(out + OFF_Z);
    {
        v4f w = {cz[0], cz[1], cz[2], cz[3]};
        __builtin_nontemporal_store(w, &oz[u]);
    }

    // ---- xy -> LDS (swizzled) ----
    lds_xy[swz(2 * t + 0)] = (v4f){cx[0], cy[0], cx[1], cy[1]};
    lds_xy[swz(2 * t + 1)] = (v4f){cx[2], cy[2], cx[3], cy[3]};

    // ---- idx -> LDS (stride-3 writes already hit all banks; no swizzle) ----
    {
        float tt[12];
#pragma unroll
        for (int j = 0; j < 4; ++j) {
            tt[3 * j + 0] = fb[j];
            tt[3 * j + 1] = fx[j];
            tt[3 * j + 2] = fy[j];
        }
        lds_idx[3 * t + 0] = (v4f){tt[0], tt[1], tt[2],  tt[3]};
        lds_idx[3 * t + 1] = (v4f){tt[4], tt[5], tt[6],  tt[7]};
        lds_idx[3 * t + 2] = (v4f){tt[8], tt[9], tt[10], tt[11]};
    }

    __syncthreads();

    // ---- dense nt global stores: 64 lanes x 16B = contiguous 1KB/instr ----
    v4f* oxy = (v4f*)out;
    __builtin_nontemporal_store(lds_xy[swz(t)],       &oxy[(long long)blk * 512 + t]);
    __builtin_nontemporal_store(lds_xy[swz(t + 256)], &oxy[(long long)blk * 512 + 256 + t]);

    v4f* oi = (v4f*)(out + OFF_IDX);
    __builtin_nontemporal_store(lds_idx[t      ], &oi[(long long)blk * 768 + t]);
    __builtin_nontemporal_store(lds_idx[t + 256], &oi[(long long)blk * 768 + 256 + t]);
    __builtin_nontemporal_store(lds_idx[t + 512], &oi[(long long)blk * 768 + 512 + t]);
}

extern "C" void kernel_launch(void* const* d_in, const int* in_sizes, int n_in,
                              void* d_out, int out_size, void* d_ws, size_t ws_size,
                              hipStream_t stream) {
    const v4f* in4 = (const v4f*)d_in[0];
    float* out = (float*)d_out;
    const int block = 256;
    const int grid  = NTH / block;  // 8704 blocks, exact
    kp_gt_kernel<<<grid, block, 0, stream>>>(in4, out);
}